// Round 1
// 608.449 us; speedup vs baseline: 2.8913x; 2.8913x over previous
//
#include <hip/hip_runtime.h>

using ushort  = unsigned short;
using bf16x8  = __attribute__((ext_vector_type(8))) __bf16;
using ushort8 = __attribute__((ext_vector_type(8))) unsigned short;
using f32x4   = __attribute__((ext_vector_type(4))) float;
using float4v = __attribute__((ext_vector_type(4))) float;

__device__ __forceinline__ float bf2f(ushort u) {
    union { unsigned int i; float f; } v; v.i = ((unsigned int)u) << 16; return v.f;
}
__device__ __forceinline__ ushort f2bf(float f) {
    union { float f; unsigned int i; } v; v.f = f;
    unsigned int r = v.i + 0x7FFFu + ((v.i >> 16) & 1u);
    return (ushort)(r >> 16);
}
__device__ __forceinline__ bf16x8 ld8(const ushort* p) {
    return __builtin_bit_cast(bf16x8, *(const ushort8*)p);
}
// async global->LDS, 16B per lane
__device__ __forceinline__ void glds16(const void* g, void* l) {
    __builtin_amdgcn_global_load_lds(
        (const __attribute__((address_space(1))) unsigned int*)g,
        (__attribute__((address_space(3))) unsigned int*)l, 16, 0, 0);
}

// ---------------------------------------------------------------------------
// Dtype sniffer: bf16 (flag=0) vs f32 (flag=1) storage, decided from `query`.
// ---------------------------------------------------------------------------
__global__ void sniff_kernel(const ushort* __restrict__ q, int* __restrict__ flag) {
    const int lane = threadIdx.x;              // 64 threads, 1 block
    float mx = 0.0f;
    for (int i = lane; i < 512; i += 64) {
        float v = bf2f(q[2 * i]);              // even halfword
        mx = fmaxf(mx, fabsf(v));
    }
#pragma unroll
    for (int off = 32; off >= 1; off >>= 1) mx = fmaxf(mx, __shfl_xor(mx, off, 64));
    if (lane == 0) *flag = (mx > 1.0e6f) ? 1 : 0;
}

// ---------------------------------------------------------------------------
// C[M=8192, N=1024] = A[M,K=1024] * W[N,K]^T + bias.
// m97-class structure: 128x128 tile, BK=32, 4 waves, 4x4 fragments/wave,
// double-buffered LDS, 1 barrier per K-step, next-tile prefetch.
// Staging: bf16 operand -> global_load_lds(16B); f32 operand -> reg-stage
// (float4 loads -> cvt to bf16 -> ds_write_b128), write placed after MFMAs.
// EPI 0: none   EPI 1: RoPE (64-col wave tile == one head)   EPI 2: sigmoid
// ABF16: A is always-bf16 workspace (ignore flag for A).
// OUTF : output is f32 when flag==1 (else bf16).
// ---------------------------------------------------------------------------
template<int EPI, int ABF16, int OUTF>
__global__ __launch_bounds__(256) void gemm_bt(
    const void* __restrict__ A, const void* __restrict__ W,
    const void* __restrict__ bias,
    const void* __restrict__ rc, const void* __restrict__ rs,
    void* __restrict__ C, const int* __restrict__ flag)
{
    constexpr int Kd = 1024, Nd = 1024;
    const bool f32m = (*flag != 0);
    const bool af32 = f32m && !ABF16;
    const bool wf32 = f32m;

    const int tid  = threadIdx.x;
    const int nb   = blockIdx.x & 7;    // N/128 = 8
    const int mb   = blockIdx.x >> 3;   // M/128 = 64
    const int wave = tid >> 6;
    const int lane = tid & 63;
    const int quad = lane >> 4;
    const int l16  = lane & 15;
    const int wr   = wave >> 1;         // 2x2 wave grid, 64x64 per wave
    const int wc   = wave & 1;

    __shared__ __align__(16) ushort As[2][128 * 32];
    __shared__ __align__(16) ushort Bs[2][128 * 32];

    const int arow0 = mb * 128;
    const int brow0 = nb * 128;

    // one 128x32 bf16 tile = 512 x 16B chunks; chunk c: row=c>>2, col8=(c&3)
    auto ldregs = [&](float4v r[4], const float* src, int row0, int k0) {
#pragma unroll
        for (int j = 0; j < 2; ++j) {
            const int c = j * 256 + tid;
            const float* gp = src + (size_t)(row0 + (c >> 2)) * Kd + k0 + (c & 3) * 8;
            r[2 * j]     = *(const float4v*)gp;
            r[2 * j + 1] = *(const float4v*)(gp + 4);
        }
    };
    auto cvtwr = [&](ushort* lds, const float4v r[4]) {
#pragma unroll
        for (int j = 0; j < 2; ++j) {
            const int c = j * 256 + tid;
            bf16x8 o;
#pragma unroll
            for (int i = 0; i < 4; ++i) {
                o[i]     = (__bf16)r[2 * j][i];
                o[i + 4] = (__bf16)r[2 * j + 1][i];
            }
            *(ushort8*)&lds[c * 8] = __builtin_bit_cast(ushort8, o);
        }
    };
    auto stage16 = [&](ushort* lds, const ushort* src, int row0, int k0) {
#pragma unroll
        for (int j = 0; j < 2; ++j) {
            const int c = j * 256 + tid;
            glds16(src + (size_t)(row0 + (c >> 2)) * Kd + k0 + (c & 3) * 8, &lds[c * 8]);
        }
    };

    // prologue: stage tile 0 into buffer 0
    {
        float4v t[4];
        if (af32) { ldregs(t, (const float*)A, arow0, 0); cvtwr(As[0], t); }
        else      stage16(As[0], (const ushort*)A, arow0, 0);
        if (wf32) { ldregs(t, (const float*)W, brow0, 0); cvtwr(Bs[0], t); }
        else      stage16(Bs[0], (const ushort*)W, brow0, 0);
    }

    f32x4 acc[4][4] = {};
    int cur = 0;
    for (int kt = 0; kt < 32; ++kt) {
        __syncthreads();                 // buf[cur] staged; buf[cur^1] free
        const bool pf = (kt < 31);
        const int  kn = (kt + 1) * 32;
        float4v ra[4], rb[4];
        if (pf) {
            if (af32) ldregs(ra, (const float*)A, arow0, kn);
            else      stage16(As[cur ^ 1], (const ushort*)A, arow0, kn);
            if (wf32) ldregs(rb, (const float*)W, brow0, kn);
            else      stage16(Bs[cur ^ 1], (const ushort*)W, brow0, kn);
        }
        bf16x8 fa[4], fb[4];
#pragma unroll
        for (int mi = 0; mi < 4; ++mi)
            fa[mi] = ld8(&As[cur][(wr * 64 + mi * 16 + l16) * 32 + quad * 8]);
#pragma unroll
        for (int ni = 0; ni < 4; ++ni)
            fb[ni] = ld8(&Bs[cur][(wc * 64 + ni * 16 + l16) * 32 + quad * 8]);
#pragma unroll
        for (int mi = 0; mi < 4; ++mi)
#pragma unroll
            for (int ni = 0; ni < 4; ++ni)
                acc[mi][ni] = __builtin_amdgcn_mfma_f32_16x16x32_bf16(fa[mi], fb[ni], acc[mi][ni], 0, 0, 0);
        if (pf) {                        // write-late (T14): vmcnt stall after MFMAs
            if (af32) cvtwr(As[cur ^ 1], ra);
            if (wf32) cvtwr(Bs[cur ^ 1], rb);
        }
        cur ^= 1;
    }

    // epilogue: bias + EPI + store.  C/D map: col=l16, row=quad*4+r
    const bool of32 = OUTF && f32m;
    const int colbase = nb * 128 + wc * 64;
    float bv[4];
#pragma unroll
    for (int ni = 0; ni < 4; ++ni) {
        const int cg = colbase + ni * 16 + l16;
        bv[ni] = wf32 ? ((const float*)bias)[cg] : bf2f(((const ushort*)bias)[cg]);
    }
    const int rowb = mb * 128 + wr * 64 + quad * 4;
#pragma unroll
    for (int mi = 0; mi < 4; ++mi) {
#pragma unroll
        for (int r = 0; r < 4; ++r) {
            const int rowg = rowb + mi * 16 + r;   // == b*1024 + pos
            float v[4];
#pragma unroll
            for (int ni = 0; ni < 4; ++ni) v[ni] = acc[mi][ni][r] + bv[ni];
            if constexpr (EPI == 1) {
                // wave col-tile is exactly one head of 64: pair j with j+32
#pragma unroll
                for (int t = 0; t < 2; ++t) {
                    const size_t ci = (size_t)rowg * 64 + t * 16 + l16;
                    const float c = f32m ? ((const float*)rc)[ci] : bf2f(((const ushort*)rc)[ci]);
                    const float s = f32m ? ((const float*)rs)[ci] : bf2f(((const ushort*)rs)[ci]);
                    const float x1 = v[t], x2 = v[t + 2];
                    v[t]     = x1 * c - x2 * s;
                    v[t + 2] = x2 * c + x1 * s;
                }
            } else if constexpr (EPI == 2) {
#pragma unroll
                for (int t = 0; t < 4; ++t) v[t] = 1.0f / (1.0f + __expf(-v[t]));
            }
#pragma unroll
            for (int ni = 0; ni < 4; ++ni) {
                const size_t idx = (size_t)rowg * Nd + colbase + ni * 16 + l16;
                if (of32) ((float*)C)[idx] = v[ni];
                else      ((ushort*)C)[idx] = f2bf(v[ni]);
            }
        }
    }
}

// ---------------------------------------------------------------------------
// Flash attention: 1 wave per (b, h, 16-row q-tile). 32-key blocks,
// online softmax, P->A-layout via LDS, V staged in LDS. Gate fused.
// Only touches bf16 workspace -> dtype-mode independent. (Unchanged.)
// ---------------------------------------------------------------------------
__global__ __launch_bounds__(64) void attn_kernel(
    const ushort* __restrict__ Qp, const ushort* __restrict__ Kp,
    const ushort* __restrict__ Vp, const ushort* __restrict__ G,
    const unsigned char* __restrict__ mask, ushort* __restrict__ O)
{
    const int qt = blockIdx.x & 63;          // Lq/16
    const int h  = (blockIdx.x >> 6) & 15;
    const int b  = blockIdx.x >> 10;
    const int lane = threadIdx.x;
    const int quad = lane >> 4;
    const int l16  = lane & 15;
    const size_t Dm = 1024;

    __shared__ __align__(16) ushort ldsP[16*32];
    __shared__ __align__(16) ushort ldsV[32*64];

    const ushort* Qb = Qp + ((size_t)b*1024 + (size_t)qt*16 + l16)*Dm + h*64 + quad*8;
    const bf16x8 qa0 = ld8(Qb);
    const bf16x8 qa1 = ld8(Qb + 32);

    float m_r[4], l_r[4];
    f32x4 o[4] = {};
#pragma unroll
    for (int r = 0; r < 4; ++r) { m_r[r] = -3.0e38f; l_r[r] = 0.0f; }

    const float scale = 0.125f;   // 1/sqrt(64)
    for (int k0 = 0; k0 < 1024; k0 += 32) {
        // stage V block (32 keys x 64 hd) into LDS
        const ushort* Vb = Vp + ((size_t)b*1024 + k0)*Dm + h*64;
#pragma unroll
        for (int c2 = 0; c2 < 4; ++c2) {
            const int idx = c2*512 + lane*8;
            const int vr = idx >> 6, vc = idx & 63;
            *(ushort8*)&ldsV[idx] = *(const ushort8*)(Vb + (size_t)vr*Dm + vc);
        }
        // S = Q K^T  (two 16-col tiles)
        f32x4 s[2] = {};
#pragma unroll
        for (int ct = 0; ct < 2; ++ct) {
            const ushort* Kb = Kp + ((size_t)b*1024 + k0 + ct*16 + l16)*Dm + h*64 + quad*8;
            s[ct] = __builtin_amdgcn_mfma_f32_16x16x32_bf16(qa0, ld8(Kb),      s[ct], 0,0,0);
            s[ct] = __builtin_amdgcn_mfma_f32_16x16x32_bf16(qa1, ld8(Kb + 32), s[ct], 0,0,0);
        }
        const bool msk0 = mask[(size_t)b*1024 + k0 + l16] != 0;
        const bool msk1 = mask[(size_t)b*1024 + k0 + 16 + l16] != 0;
        __syncthreads();
        // online softmax per q-row (row = quad*4 + r)
#pragma unroll
        for (int r = 0; r < 4; ++r) {
            float s0 = msk0 ? -1e30f : s[0][r]*scale;
            float s1 = msk1 ? -1e30f : s[1][r]*scale;
            float mx = fmaxf(s0, s1);
#pragma unroll
            for (int off = 8; off >= 1; off >>= 1) mx = fmaxf(mx, __shfl_xor(mx, off, 16));
            const float mnew  = fmaxf(m_r[r], mx);
            const float alpha = __expf(m_r[r] - mnew);
            const float p0 = __expf(s0 - mnew), p1 = __expf(s1 - mnew);
            float ps = p0 + p1;
#pragma unroll
            for (int off = 8; off >= 1; off >>= 1) ps += __shfl_xor(ps, off, 16);
            l_r[r] = l_r[r]*alpha + ps;
            m_r[r] = mnew;
#pragma unroll
            for (int t = 0; t < 4; ++t) o[t][r] *= alpha;
            ldsP[(quad*4 + r)*32 + l16]      = f2bf(p0);
            ldsP[(quad*4 + r)*32 + 16 + l16] = f2bf(p1);
        }
        __syncthreads();
        // O += P V
        const bf16x8 pa = __builtin_bit_cast(bf16x8, *(const ushort8*)&ldsP[l16*32 + quad*8]);
#pragma unroll
        for (int t = 0; t < 4; ++t) {
            ushort8 tmp;
#pragma unroll
            for (int j = 0; j < 8; ++j) tmp[j] = ldsV[(quad*8 + j)*64 + t*16 + l16];
            o[t] = __builtin_amdgcn_mfma_f32_16x16x32_bf16(pa, __builtin_bit_cast(bf16x8, tmp), o[t], 0,0,0);
        }
        __syncthreads();
    }
    // epilogue: normalize, gate, store bf16
    const int rowg0 = b*1024 + qt*16 + quad*4;
#pragma unroll
    for (int r = 0; r < 4; ++r) {
        const float inv = 1.0f / l_r[r];
#pragma unroll
        for (int t = 0; t < 4; ++t) {
            const size_t idx = (size_t)(rowg0 + r)*Dm + h*64 + t*16 + l16;
            O[idx] = f2bf(o[t][r] * inv * bf2f(G[idx]));
        }
    }
}

extern "C" void kernel_launch(void* const* d_in, const int* in_sizes, int n_in,
                              void* d_out, int out_size, void* d_ws, size_t ws_size,
                              hipStream_t stream)
{
    const void* query = d_in[0];
    const void* key   = d_in[1];
    const void* value = d_in[2];
    const void* Wq    = d_in[3];
    const void* bq    = d_in[4];
    const void* Wk    = d_in[5];
    const void* bk    = d_in[6];
    const void* Wv    = d_in[7];
    const void* bv    = d_in[8];
    const void* Wg    = d_in[9];
    const void* bg    = d_in[10];
    const void* Wo    = d_in[11];
    const void* bo    = d_in[12];
    const void* rc    = d_in[13];
    const void* rs    = d_in[14];
    const unsigned char* mask = (const unsigned char*)d_in[15];

    char* ws = (char*)d_ws;
    const size_t MB16 = (size_t)16 << 20;        // 8192*1024*2 bytes
    ushort* Qp = (ushort*)(ws);
    ushort* Kp = (ushort*)(ws + 1*MB16);
    ushort* Vp = (ushort*)(ws + 2*MB16);
    ushort* Gt = (ushort*)(ws + 3*MB16);
    ushort* Ag = (ushort*)(ws + 4*MB16);
    int*  flag = (int*)(ws + 5*MB16);

    const dim3 gb(512), gt(256);
    hipLaunchKernelGGL(sniff_kernel, dim3(1), dim3(64), 0, stream, (const ushort*)query, flag);

    hipLaunchKernelGGL((gemm_bt<1,0,0>), gb, gt, 0, stream, query, Wq, bq, rc, rs, Qp, flag);
    hipLaunchKernelGGL((gemm_bt<1,0,0>), gb, gt, 0, stream, key,   Wk, bk, rc, rs, Kp, flag);
    hipLaunchKernelGGL((gemm_bt<0,0,0>), gb, gt, 0, stream, value, Wv, bv, rc, rs, Vp, flag);
    hipLaunchKernelGGL((gemm_bt<2,0,0>), gb, gt, 0, stream, query, Wg, bg, rc, rs, Gt, flag);

    hipLaunchKernelGGL(attn_kernel, dim3(8192), dim3(64), 0, stream, Qp, Kp, Vp, Gt, mask, Ag);

    // final projection: A (=Ag) is always bf16 workspace; W/bias + output follow mode
    hipLaunchKernelGGL((gemm_bt<0,1,1>), gb, gt, 0, stream, Ag, Wo, bo, rc, rs, d_out, flag);
}